// Round 5
// baseline (1406.461 us; speedup 1.0000x reference)
//
#include <hip/hip_runtime.h>

typedef __bf16 bf16;
typedef __bf16 bf16x8 __attribute__((ext_vector_type(8)));
typedef float f32x4 __attribute__((ext_vector_type(4)));

typedef __attribute__((address_space(3))) void lds_void_t;
typedef const __attribute__((address_space(1))) void gbl_void_t;

#define TOK 4096
#define KBROWS 5120

enum { M_BF16 = 0, M_F32 = 1, M_RELU = 2, M_QKV = 3, M_SCORES = 4 };

struct GemmArgs {
  const bf16* A; long long sAe, sAi; int ldA;
  const bf16* B; long long sBe, sBi; int ldB;
  const bf16* B2; long long sB2e; int ldB2;
  bf16* C; float* Cf; long long sCe, sCi; int ldC;
  int M, N, K, iPerE;
  bf16 *quv, *kbuf, *vt;
  const float *uvA, *uvB;
  float scale;
};

// ---------------- GEMM: C = A @ B^T, A (MxK) row-major, B (NxK) row-major ----------------
// Staging via global_load_lds (async direct-to-LDS, 16B/lane). Lane (8r+c) fetches global
// chunk c^r -> LDS holds the XOR-swizzled layout; frag reads sw=(4s+quad)^l7 are 0-conflict.
// launch_bounds(256,4): 4 waves/EU -> 4 blocks/CU (VGPR 44+64acc=108<=128; LDS 32KBx4<=160KB).
template<int MODE, bool SPLITB, int TM, int TN>
__global__ __launch_bounds__(256, 4)
void gemm_kernel(GemmArgs g) {
  constexpr int FA = TM / 32, FB = TN / 32;
  int z = blockIdx.z;
  int e = z / g.iPerE;
  int i = z % g.iPerE;
  const bf16* A = g.A + e * g.sAe + i * g.sAi;
  const bf16* B = g.B + e * g.sBe + i * g.sBi;
  const bf16* B2 = nullptr;
  if constexpr (SPLITB) B2 = g.B2 + e * g.sB2e;

  int tm = blockIdx.x * TM;
  int tn = blockIdx.y * TN;

  __shared__ uint4 As4[TM * 8];
  __shared__ uint4 Bs4[TN * 8];
  bf16* As_lds = (bf16*)As4;
  bf16* Bs_lds = (bf16*)Bs4;

  int tid = threadIdx.x;
  int wave = tid >> 6, lane = tid & 63;
  int wm = (wave >> 1) * (TM / 2), wn = (wave & 1) * (TN / 2);
  int quad = lane >> 4, l15 = lane & 15;
  int l7 = l15 & 7;
  int l8r = lane >> 3, l8c = lane & 7;
  int fc = l8c ^ l8r;              // swizzled fetch chunk (row&7 == l8r, since rowbase%8==0)

  f32x4 acc[FA][FB] = {};

  for (int k0 = 0; k0 < g.K; k0 += 64) {
#pragma unroll
    for (int ii = 0; ii < FA; ++ii) {
      int rowbase = (wave * FA + ii) * 8;
      int r = rowbase + l8r;
      const bf16* gp = &A[(long long)(tm + r) * g.ldA + k0 + fc * 8];
      __builtin_amdgcn_global_load_lds((gbl_void_t*)gp, (lds_void_t*)&As_lds[rowbase * 64], 16, 0, 0);
    }
#pragma unroll
    for (int ii = 0; ii < FB; ++ii) {
      int rowbase = (wave * FB + ii) * 8;
      int r = rowbase + l8r;
      const bf16* gp;
      if constexpr (SPLITB) {
        int kk = k0 + fc * 8;
        gp = (kk < 512) ? &B[(long long)(tn + r) * g.ldB + kk]
                        : &B2[(long long)(tn + r) * g.ldB2 + (kk - 512)];
      } else {
        gp = &B[(long long)(tn + r) * g.ldB + k0 + fc * 8];
      }
      __builtin_amdgcn_global_load_lds((gbl_void_t*)gp, (lds_void_t*)&Bs_lds[rowbase * 64], 16, 0, 0);
    }
    __syncthreads();
#pragma unroll
    for (int s = 0; s < 2; ++s) {
      int sw = (s * 4 + quad) ^ l7;
      bf16x8 af[FA], bfr[FB];
#pragma unroll
      for (int t = 0; t < FA; ++t) af[t]  = ((const bf16x8*)As4)[(wm + t * 16 + l15) * 8 + sw];
#pragma unroll
      for (int t = 0; t < FB; ++t) bfr[t] = ((const bf16x8*)Bs4)[(wn + t * 16 + l15) * 8 + sw];
#pragma unroll
      for (int a = 0; a < FA; ++a)
#pragma unroll
        for (int b = 0; b < FB; ++b)
          acc[a][b] = __builtin_amdgcn_mfma_f32_16x16x32_bf16(af[a], bfr[b], acc[a][b], 0, 0, 0);
    }
    __syncthreads();
  }

  // epilogues. C/D layout: col = lane&15, row = quad*4 + reg (m89-verified)
  if constexpr (MODE == M_QKV) {
    const float* uv = e ? g.uvB : g.uvA;
#pragma unroll
    for (int a = 0; a < FA; ++a) {
      int mB = tm + wm + a * 16 + quad * 4;
#pragma unroll
      for (int b = 0; b < FB; ++b) {
        int col = tn + wn + b * 16 + l15;
        int region = col >> 9, cin = col & 511;
        float u0 = 0.f, v0 = 0.f;
        if (region == 0) { u0 = uv[cin]; v0 = uv[512 + cin]; }
#pragma unroll
        for (int r = 0; r < 4; ++r) {
          int m = mB + r;
          float val = acc[a][b][r];
          if (region == 0) {
            long long qb = (long long)e * TOK * 1024 + (long long)m * 1024;
            g.quv[qb + cin]       = (bf16)(val + u0);
            g.quv[qb + 512 + cin] = (bf16)(val + v0);
          } else if (region == 1) {
            g.kbuf[(long long)e * KBROWS * 512 + (long long)(1024 + m) * 512 + cin] = (bf16)val;
          } else {  // V row-major (vbuf), rows 0..4095
            g.vt[(long long)e * TOK * 512 + (long long)m * 512 + cin] = (bf16)val;
          }
        }
      }
    }
  } else if constexpr (MODE == M_SCORES) {
    bf16* C = g.C + e * g.sCe + i * g.sCi;
    int T = 1024 - ((i < 2 ? i : 2) << 9);   // mask cols < T
#pragma unroll
    for (int a = 0; a < FA; ++a) {
      int mB = tm + wm + a * 16 + quad * 4;
#pragma unroll
      for (int b = 0; b < FB; ++b) {
        int col = tn + wn + b * 16 + l15;
        float bias = (col < T) ? -1e9f : 0.0f;
#pragma unroll
        for (int r = 0; r < 4; ++r)
          C[(long long)(mB + r) * g.ldC + col] = (bf16)(acc[a][b][r] * g.scale + bias);
      }
    }
  } else {
#pragma unroll
    for (int a = 0; a < FA; ++a) {
      int mB = tm + wm + a * 16 + quad * 4;
#pragma unroll
      for (int b = 0; b < FB; ++b) {
        int col = tn + wn + b * 16 + l15;
#pragma unroll
        for (int r = 0; r < 4; ++r) {
          float val = acc[a][b][r];
          if constexpr (MODE == M_RELU) val = val > 0.f ? val : 0.f;
          if constexpr (MODE == M_F32) {
            float* Cf = g.Cf + e * g.sCe + i * g.sCi;
            Cf[(long long)(mB + r) * g.ldC + col] = val;
          } else {
            bf16* C = g.C + e * g.sCe + i * g.sCi;
            C[(long long)(mB + r) * g.ldC + col] = (bf16)val;
          }
        }
      }
    }
  }
}

// ---------------- weight transpose + f32->bf16 ----------------
__global__ __launch_bounds__(256)
void transpose_conv(const float* src, bf16* dst, int R, int C) {
  __shared__ bf16 t[64][65];
  int c0 = blockIdx.x * 64, r0 = blockIdx.y * 64;
  long long b = blockIdx.z;
  const float* s = src + b * (long long)R * C;
  bf16* d = dst + b * (long long)R * C;
  int x = threadIdx.x, y = threadIdx.y;
  for (int k = 0; k < 16; ++k) {
    int rr = y + k * 4;
    t[rr][x] = (bf16)s[(long long)(r0 + rr) * C + c0 + x];
  }
  __syncthreads();
  for (int k = 0; k < 16; ++k) {
    int rr = y + k * 4;
    d[(long long)(c0 + rr) * R + r0 + x] = t[x][rr];
  }
}

__global__ __launch_bounds__(256)
void transpose_qkvr(const float* qa, const float* qb, bf16* wqkvT, bf16* wrT) {
  __shared__ bf16 t[64][65];
  int z = blockIdx.z;
  int e = z / 24, rj = z % 24, j = rj / 4, c = rj % 4;
  const float* s = (e ? qb : qa) + (long long)(j * 4 + c) * 512 * 512;
  bf16* d = (c < 3) ? wqkvT + (long long)((e * 6 + j) * 3 + c) * 512 * 512
                    : wrT + (long long)(e * 6 + j) * 512 * 512;
  int c0 = blockIdx.x * 64, r0 = blockIdx.y * 64;
  int x = threadIdx.x, y = threadIdx.y;
  for (int k = 0; k < 16; ++k) {
    int rr = y + k * 4;
    t[rr][x] = (bf16)s[(long long)(r0 + rr) * 512 + c0 + x];
  }
  __syncthreads();
  for (int k = 0; k < 16; ++k) {
    int rr = y + k * 4;
    d[(long long)(c0 + rr) * 512 + r0 + x] = t[x][rr];
  }
}

// ---------------- misc setup kernels ----------------
__global__ __launch_bounds__(256)
void sinusoid_kernel(bf16* rb) {
  int i = blockIdx.x, m = threadIdx.x;
  float p = (float)(1535 - i);
  float inv = expf(-((float)(2 * m) * (1.0f / 512.0f)) * 9.210340371976184f);
  float ang = p * inv;
  rb[(long long)i * 512 + 2 * m]     = (bf16)sinf(ang);
  rb[(long long)i * 512 + 2 * m + 1] = (bf16)cosf(ang);
}

__global__ __launch_bounds__(128)
void embed_kernel(const int* src, const float* emb, bf16* Sb, float* Sf) {
  int row = blockIdx.x, e = blockIdx.y, tid = threadIdx.x;
  int tok = e ? src[4095 - row] : src[row];
  long long base = ((long long)e * TOK + row) * 512 + tid * 4;
  float4 f = *(const float4*)&emb[(long long)tok * 512 + tid * 4];
  *(float4*)&Sf[base] = f;
  Sb[base + 0] = (bf16)f.x; Sb[base + 1] = (bf16)f.y;
  Sb[base + 2] = (bf16)f.z; Sb[base + 3] = (bf16)f.w;
}

// zero the "no-memory" regions: kbuf rows 0..1023, vwoT cols 0..1023
__global__ __launch_bounds__(256)
void zero_kv(bf16* kbuf, bf16* vwoT) {
  int r = blockIdx.x, e = blockIdx.y, which = blockIdx.z, tid = threadIdx.x;
  if (which == 0) {
    bf16* p = kbuf + ((long long)e * KBROWS + r) * 512;
    p[tid] = (bf16)0.f; p[tid + 256] = (bf16)0.f;
  } else if (r < 512) {
    bf16* p = vwoT + ((long long)e * 512 + r) * KBROWS;
#pragma unroll
    for (int k = 0; k < 4; ++k) p[tid + k * 256] = (bf16)0.f;
  }
}

// ---------------- softmax (in-place on bf16 scores) ----------------
__global__ __launch_bounds__(256)
void softmax_kernel(bf16* P) {
  long long base = (((long long)blockIdx.z * 8 + blockIdx.y) * 512 + blockIdx.x) * 1536;
  bf16* p = P + base;
  int tid = threadIdx.x;
  float v[6];
  float mx = -3e38f;
#pragma unroll
  for (int k = 0; k < 6; ++k) { v[k] = (float)p[tid + (k << 8)]; mx = fmaxf(mx, v[k]); }
  for (int off = 32; off; off >>= 1) mx = fmaxf(mx, __shfl_xor(mx, off));
  __shared__ float red[8];
  int wv = tid >> 6;
  if ((tid & 63) == 0) red[wv] = mx;
  __syncthreads();
  mx = fmaxf(fmaxf(red[0], red[1]), fmaxf(red[2], red[3]));
  float sum = 0.f;
#pragma unroll
  for (int k = 0; k < 6; ++k) { v[k] = __expf(v[k] - mx); sum += v[k]; }
  for (int off = 32; off; off >>= 1) sum += __shfl_xor(sum, off);
  if ((tid & 63) == 0) red[4 + wv] = sum;
  __syncthreads();
  sum = red[4] + red[5] + red[6] + red[7];
  float inv = 1.0f / sum;
#pragma unroll
  for (int k = 0; k < 6; ++k) p[tid + (k << 8)] = (bf16)(v[k] * inv);
}

// ---------------- residual + layernorm (fp32 in, dual-store bf16+fp32; in-place safe) ----------------
__global__ __launch_bounds__(64)
void ln_kernel(const float* Xf, const float* Tf, const float* lnA, const float* lnB,
               int gOff, bf16* OutB, float* OutF) {
  int row = blockIdx.x, e = blockIdx.y;
  long long base = ((long long)e * TOK + row) * 512;
  const float* x = Xf + base;
  const float* t = Tf + base;
  const float* ln = e ? lnB : lnA;
  const float* gm = ln + gOff;
  const float* bt = ln + gOff + 512;
  int lane = threadIdx.x;
  float vals[8];
  float s = 0.f;
#pragma unroll
  for (int k = 0; k < 8; ++k) { int d = lane + k * 64; vals[k] = x[d] + t[d]; s += vals[k]; }
  for (int off = 32; off; off >>= 1) s += __shfl_xor(s, off);
  float mu = s * (1.0f / 512.0f);
  float vs = 0.f;
#pragma unroll
  for (int k = 0; k < 8; ++k) { float d0 = vals[k] - mu; vs += d0 * d0; }
  for (int off = 32; off; off >>= 1) vs += __shfl_xor(vs, off);
  float rstd = rsqrtf(vs * (1.0f / 512.0f) + 1e-5f);
#pragma unroll
  for (int k = 0; k < 8; ++k) {
    int d = lane + k * 64;
    float y = (vals[k] - mu) * rstd * gm[d] + bt[d];
    OutB[base + d] = (bf16)y;
    OutF[base + d] = y;
  }
}

// ---------------- final concat + bf16->fp32 ----------------
__global__ __launch_bounds__(256)
void final_kernel(const bf16* Sb, float* out) {
  int row = blockIdx.x, tid = threadIdx.x;
#pragma unroll
  for (int k = 0; k < 4; ++k) {
    int col = tid + k * 256;
    float val;
    if (col < 512) val = (float)Sb[(long long)row * 512 + col];
    else val = (float)Sb[(long long)(TOK + (4095 - row)) * 512 + (col - 512)];
    out[(long long)row * 1024 + col] = val;
  }
}

extern "C" void kernel_launch(void* const* d_in, const int* in_sizes, int n_in,
                              void* d_out, int out_size, void* d_ws, size_t ws_size,
                              hipStream_t stream) {
  const int*   src   = (const int*)d_in[0];
  const float* emb   = (const float*)d_in[2];
  const float* Wq_a  = (const float*)d_in[3];
  const float* Wo_a  = (const float*)d_in[4];
  const float* W1_a  = (const float*)d_in[5];
  const float* W2_a  = (const float*)d_in[6];
  const float* ln_a  = (const float*)d_in[7];
  const float* uv_a  = (const float*)d_in[8];
  const float* Wq_b  = (const float*)d_in[9];
  const float* Wo_b  = (const float*)d_in[10];
  const float* W1_b  = (const float*)d_in[11];
  const float* W2_b  = (const float*)d_in[12];
  const float* ln_b  = (const float*)d_in[13];
  const float* uv_b  = (const float*)d_in[14];
  float* out = (float*)d_out;

  char* w = (char*)d_ws;
  size_t off = 0;
  auto alloc = [&](long long elems, int esz) -> char* {
    char* p = w + off;
    off += (size_t)elems * esz;
    off = (off + 255) & ~(size_t)255;
    return p;
  };
  bf16* wqkvT = (bf16*)alloc(2LL * 6 * 1536 * 512, 2);
  bf16* woT   = (bf16*)alloc(2LL * 6 * 512 * 512, 2);
  bf16* w1T   = (bf16*)alloc(2LL * 6 * 2048 * 512, 2);
  bf16* w2T   = (bf16*)alloc(2LL * 6 * 512 * 2048, 2);
  bf16* pk    = (bf16*)alloc(2LL * 6 * 1536 * 512, 2);
  bf16* Sb    = (bf16*)alloc(2LL * TOK * 512, 2);
  float* Sf   = (float*)alloc(2LL * TOK * 512, 4);
  bf16* quv   = (bf16*)alloc(2LL * TOK * 1024, 2);
  bf16* kbuf  = (bf16*)alloc(2LL * KBROWS * 512, 2);
  bf16* vwoT  = (bf16*)alloc(2LL * 512 * KBROWS, 2);
  bf16* P     = (bf16*)alloc(2LL * 8 * 512 * 1536, 2);
  float* t1f  = (float*)alloc(2LL * TOK * 512, 4);
  bf16* f1    = (bf16*)alloc(2LL * TOK * 2048, 2);
  // overlays (lifetime-disjoint):
  bf16* rb    = f1;                   // setup only
  bf16* wrT   = f1 + 1024LL * 1024;   // setup only
  bf16* vbuf  = P;                    // V rows (2 x 4096 x 512); dead before scores writes P

  if (off > ws_size) return;

  // ---- setup ----
  transpose_qkvr<<<dim3(8, 8, 48), dim3(64, 4), 0, stream>>>(Wq_a, Wq_b, wqkvT, wrT);
  transpose_conv<<<dim3(8, 8, 6),  dim3(64, 4), 0, stream>>>(Wo_a, woT, 512, 512);
  transpose_conv<<<dim3(8, 8, 6),  dim3(64, 4), 0, stream>>>(Wo_b, woT + 6LL * 512 * 512, 512, 512);
  transpose_conv<<<dim3(32, 8, 6), dim3(64, 4), 0, stream>>>(W1_a, w1T, 512, 2048);
  transpose_conv<<<dim3(32, 8, 6), dim3(64, 4), 0, stream>>>(W1_b, w1T + 6LL * 2048 * 512, 512, 2048);
  transpose_conv<<<dim3(8, 32, 6), dim3(64, 4), 0, stream>>>(W2_a, w2T, 2048, 512);
  transpose_conv<<<dim3(8, 32, 6), dim3(64, 4), 0, stream>>>(W2_b, w2T + 6LL * 512 * 2048, 2048, 512);
  sinusoid_kernel<<<1536, 256, 0, stream>>>(rb);
  embed_kernel<<<dim3(4096, 2), 128, 0, stream>>>(src, emb, Sb, Sf);
  zero_kv<<<dim3(1024, 2, 2), 256, 0, stream>>>(kbuf, vwoT);

  {  // pk[e][j] = R @ Wr[e][j]
    GemmArgs g = {};
    g.A = rb; g.sAe = 0; g.sAi = 0; g.ldA = 512;
    g.B = wrT; g.sBe = 0; g.sBi = 512LL * 512; g.ldB = 512;
    g.C = pk; g.sCe = 0; g.sCi = 1536LL * 512; g.ldC = 512;
    g.M = 1536; g.N = 512; g.K = 512; g.iPerE = 12;
    gemm_kernel<M_BF16, false, 128, 128><<<dim3(12, 4, 12), 256, 0, stream>>>(g);
  }

  const float scale = 0.044194173824159216f;  // 1/sqrt(512)

  for (int j = 0; j < 6; ++j) {
    {  // QKV fused: q+u/q+v -> quv, k -> kbuf(+1024 rows), v -> vbuf (row-major)
      GemmArgs g = {};
      g.A = Sb; g.sAe = (long long)TOK * 512; g.sAi = 0; g.ldA = 512;
      g.B = wqkvT + (long long)j * 1536 * 512; g.sBe = 6LL * 1536 * 512; g.sBi = 0; g.ldB = 512;
      g.M = TOK; g.N = 1536; g.K = 512; g.iPerE = 1;
      g.quv = quv; g.kbuf = kbuf; g.vt = vbuf; g.uvA = uv_a; g.uvB = uv_b;
      gemm_kernel<M_QKV, false, 128, 128><<<dim3(32, 12, 2), 256, 0, stream>>>(g);
    }
    {  // vwoT[od][1024+n] = Wo^T @ V^T   (=> PV later yields attn@Wo directly)
      GemmArgs g = {};
      g.A = woT + (long long)j * 512 * 512; g.sAe = 6LL * 512 * 512; g.sAi = 0; g.ldA = 512;
      g.B = vbuf; g.sBe = (long long)TOK * 512; g.sBi = 0; g.ldB = 512;
      g.C = vwoT + 1024; g.sCe = 512LL * KBROWS; g.sCi = 0; g.ldC = KBROWS;
      g.M = 512; g.N = TOK; g.K = 512; g.iPerE = 1;
      gemm_kernel<M_BF16, false, 64, 128><<<dim3(8, 32, 2), 256, 0, stream>>>(g);
    }
    {  // scores = qu@Kwin^T + qv@pk^T, scale+mask fused, bf16 out
      GemmArgs g = {};
      g.A = quv; g.sAe = (long long)TOK * 1024; g.sAi = 512LL * 1024; g.ldA = 1024;
      g.B = kbuf; g.sBe = (long long)KBROWS * 512; g.sBi = 512LL * 512; g.ldB = 512;
      g.B2 = pk + (long long)j * 1536 * 512; g.sB2e = 6LL * 1536 * 512; g.ldB2 = 512;
      g.C = P; g.sCe = 8LL * 512 * 1536; g.sCi = 512LL * 1536; g.ldC = 1536;
      g.M = 512; g.N = 1536; g.K = 1024; g.iPerE = 8;
      g.scale = scale;
      gemm_kernel<M_SCORES, true, 128, 128><<<dim3(4, 12, 16), 256, 0, stream>>>(g);
    }
    softmax_kernel<<<dim3(512, 8, 2), 256, 0, stream>>>(P);
    {  // attn_proj = P @ (V@Wo)win  -> fp32 t1f directly
      GemmArgs g = {};
      g.A = P; g.sAe = 8LL * 512 * 1536; g.sAi = 512LL * 1536; g.ldA = 1536;
      g.B = vwoT; g.sBe = 512LL * KBROWS; g.sBi = 512; g.ldB = KBROWS;
      g.Cf = t1f; g.sCe = (long long)TOK * 512; g.sCi = 512LL * 512; g.ldC = 512;
      g.M = 512; g.N = 512; g.K = 1536; g.iPerE = 8;
      gemm_kernel<M_F32, false, 64, 128><<<dim3(8, 4, 16), 256, 0, stream>>>(g);
    }
    // H = LN(state + attn_out) — in-place into Sb/Sf
    ln_kernel<<<dim3(4096, 2), 64, 0, stream>>>(Sf, t1f, ln_a, ln_b, (j * 4 + 0) * 512, Sb, Sf);
    {  // F1 = relu(H @ W1)
      GemmArgs g = {};
      g.A = Sb; g.sAe = (long long)TOK * 512; g.sAi = 0; g.ldA = 512;
      g.B = w1T + (long long)j * 2048 * 512; g.sBe = 6LL * 2048 * 512; g.sBi = 0; g.ldB = 512;
      g.C = f1; g.sCe = (long long)TOK * 2048; g.sCi = 0; g.ldC = 2048;
      g.M = TOK; g.N = 2048; g.K = 512; g.iPerE = 1;
      gemm_kernel<M_RELU, false, 128, 128><<<dim3(32, 16, 2), 256, 0, stream>>>(g);
    }
    {  // T1 = F1 @ W2 (fp32 out), 64x128 tiles -> 512 blocks
      GemmArgs g = {};
      g.A = f1; g.sAe = (long long)TOK * 2048; g.sAi = 0; g.ldA = 2048;
      g.B = w2T + (long long)j * 512 * 2048; g.sBe = 6LL * 512 * 2048; g.sBi = 0; g.ldB = 2048;
      g.Cf = t1f; g.sCe = (long long)TOK * 512; g.sCi = 0; g.ldC = 512;
      g.M = TOK; g.N = 512; g.K = 2048; g.iPerE = 1;
      gemm_kernel<M_F32, false, 64, 128><<<dim3(64, 4, 2), 256, 0, stream>>>(g);
    }
    // state = LN(H + ff) — in-place into Sb/Sf
    ln_kernel<<<dim3(4096, 2), 64, 0, stream>>>(Sf, t1f, ln_a, ln_b, (j * 4 + 2) * 512, Sb, Sf);
  }
  final_kernel<<<4096, 256, 0, stream>>>(Sb, out);
}

// Round 6
// 1292.071 us; speedup vs baseline: 1.0885x; 1.0885x over previous
//
#include <hip/hip_runtime.h>

typedef __bf16 bf16;
typedef __bf16 bf16x8 __attribute__((ext_vector_type(8)));
typedef float f32x4 __attribute__((ext_vector_type(4)));

typedef __attribute__((address_space(3))) void lds_void_t;
typedef const __attribute__((address_space(1))) void gbl_void_t;

#define TOK 4096
#define KBROWS 5120

enum { M_BF16 = 0, M_F32 = 1, M_RELU = 2, M_QKV = 3, M_SCOREXP = 4, M_PV = 5 };

struct GemmArgs {
  const bf16* A; long long sAe, sAi; int ldA;
  const bf16* B; long long sBe, sBi; int ldB;
  const bf16* B2; long long sB2e; int ldB2;
  bf16* C; float* Cf; long long sCe, sCi; int ldC;
  int M, N, K, iPerE;
  bf16 *quv, *kbuf, *vt;
  const float *uvA, *uvB;
  float scale;
};

// ---------------- GEMM: C = A @ B^T, A (MxK) row-major, B (NxK) row-major ----------------
// Staging via global_load_lds; lane (8r+c) fetches chunk c^r -> XOR-swizzled LDS, frag reads
// sw=(4s+quad)^l7 are 0-bank-conflict. M_SCOREXP: epilogue exp (bounded logits, mask->0).
// M_PV: A-frags cover each P row's full K exactly once -> row-sum l computed in-loop, /l in epi.
template<int MODE, bool SPLITB, int TM, int TN>
__global__ __launch_bounds__(256, 4)
void gemm_kernel(GemmArgs g) {
  constexpr int FA = TM / 32, FB = TN / 32;
  int z = blockIdx.z;
  int e = z / g.iPerE;
  int i = z % g.iPerE;
  const bf16* A = g.A + e * g.sAe + i * g.sAi;
  const bf16* B = g.B + e * g.sBe + i * g.sBi;
  const bf16* B2 = nullptr;
  if constexpr (SPLITB) B2 = g.B2 + e * g.sB2e;

  int tm = blockIdx.x * TM;
  int tn = blockIdx.y * TN;

  __shared__ uint4 As4[TM * 8];
  __shared__ uint4 Bs4[TN * 8];
  __shared__ float ls[MODE == M_PV ? TM : 1];
  bf16* As_lds = (bf16*)As4;
  bf16* Bs_lds = (bf16*)Bs4;

  int tid = threadIdx.x;
  int wave = tid >> 6, lane = tid & 63;
  int wm = (wave >> 1) * (TM / 2), wn = (wave & 1) * (TN / 2);
  int quad = lane >> 4, l15 = lane & 15;
  int l7 = l15 & 7;
  int l8r = lane >> 3, l8c = lane & 7;
  int fc = l8c ^ l8r;

  f32x4 acc[FA][FB] = {};
  float lreg[FA];
#pragma unroll
  for (int t = 0; t < FA; ++t) lreg[t] = 0.f;

  for (int k0 = 0; k0 < g.K; k0 += 64) {
#pragma unroll
    for (int ii = 0; ii < FA; ++ii) {
      int rowbase = (wave * FA + ii) * 8;
      int r = rowbase + l8r;
      const bf16* gp = &A[(long long)(tm + r) * g.ldA + k0 + fc * 8];
      __builtin_amdgcn_global_load_lds((gbl_void_t*)gp, (lds_void_t*)&As_lds[rowbase * 64], 16, 0, 0);
    }
#pragma unroll
    for (int ii = 0; ii < FB; ++ii) {
      int rowbase = (wave * FB + ii) * 8;
      int r = rowbase + l8r;
      const bf16* gp;
      if constexpr (SPLITB) {
        int kk = k0 + fc * 8;
        gp = (kk < 512) ? &B[(long long)(tn + r) * g.ldB + kk]
                        : &B2[(long long)(tn + r) * g.ldB2 + (kk - 512)];
      } else {
        gp = &B[(long long)(tn + r) * g.ldB + k0 + fc * 8];
      }
      __builtin_amdgcn_global_load_lds((gbl_void_t*)gp, (lds_void_t*)&Bs_lds[rowbase * 64], 16, 0, 0);
    }
    __syncthreads();
#pragma unroll
    for (int s = 0; s < 2; ++s) {
      int sw = (s * 4 + quad) ^ l7;
      bf16x8 af[FA], bfr[FB];
#pragma unroll
      for (int t = 0; t < FA; ++t) af[t]  = ((const bf16x8*)As4)[(wm + t * 16 + l15) * 8 + sw];
#pragma unroll
      for (int t = 0; t < FB; ++t) bfr[t] = ((const bf16x8*)Bs4)[(wn + t * 16 + l15) * 8 + sw];
      if constexpr (MODE == M_PV) {
#pragma unroll
        for (int t = 0; t < FA; ++t)
#pragma unroll
          for (int q2 = 0; q2 < 8; ++q2) lreg[t] += (float)af[t][q2];
      }
#pragma unroll
      for (int a = 0; a < FA; ++a)
#pragma unroll
        for (int b = 0; b < FB; ++b)
          acc[a][b] = __builtin_amdgcn_mfma_f32_16x16x32_bf16(af[a], bfr[b], acc[a][b], 0, 0, 0);
    }
    __syncthreads();
  }

  if constexpr (MODE == M_PV) {
    // rowsum l: lane holds partial of row (wm + t*16 + l15); reduce across quads
#pragma unroll
    for (int t = 0; t < FA; ++t) {
      lreg[t] += __shfl_xor(lreg[t], 16);
      lreg[t] += __shfl_xor(lreg[t], 32);
      if (quad == 0) ls[wm + t * 16 + l15] = lreg[t];
    }
    __syncthreads();
  }

  // epilogues. C/D layout: col = lane&15, row = quad*4 + reg (m89-verified)
  if constexpr (MODE == M_QKV) {
    const float* uv = e ? g.uvB : g.uvA;
#pragma unroll
    for (int a = 0; a < FA; ++a) {
      int mB = tm + wm + a * 16 + quad * 4;
#pragma unroll
      for (int b = 0; b < FB; ++b) {
        int col = tn + wn + b * 16 + l15;
        int region = col >> 9, cin = col & 511;
        float u0 = 0.f, v0 = 0.f;
        if (region == 0) { u0 = uv[cin]; v0 = uv[512 + cin]; }
#pragma unroll
        for (int r = 0; r < 4; ++r) {
          int m = mB + r;
          float val = acc[a][b][r];
          if (region == 0) {
            long long qb = (long long)e * TOK * 1024 + (long long)m * 1024;
            g.quv[qb + cin]       = (bf16)(val + u0);
            g.quv[qb + 512 + cin] = (bf16)(val + v0);
          } else if (region == 1) {
            g.kbuf[(long long)e * KBROWS * 512 + (long long)(1024 + m) * 512 + cin] = (bf16)val;
          } else {  // region 2: S@Wvo -> vwoT[od][1024+token] (transposed scatter)
            g.vt[(long long)e * 512 * KBROWS + (long long)cin * KBROWS + 1024 + m] = (bf16)val;
          }
        }
      }
    }
  } else if constexpr (MODE == M_SCOREXP) {
    bf16* C = g.C + e * g.sCe + i * g.sCi;
    int T = 1024 - ((i < 2 ? i : 2) << 9);   // mask cols < T
#pragma unroll
    for (int a = 0; a < FA; ++a) {
      int mB = tm + wm + a * 16 + quad * 4;
#pragma unroll
      for (int b = 0; b < FB; ++b) {
        int col = tn + wn + b * 16 + l15;
        float bias = (col < T) ? -1e9f : 0.0f;
#pragma unroll
        for (int r = 0; r < 4; ++r)
          C[(long long)(mB + r) * g.ldC + col] = (bf16)__expf(acc[a][b][r] * g.scale + bias);
      }
    }
  } else if constexpr (MODE == M_PV) {
    float* Cf = g.Cf + e * g.sCe + i * g.sCi;
#pragma unroll
    for (int a = 0; a < FA; ++a) {
      int lrow = wm + a * 16 + quad * 4;
      int mB = tm + lrow;
#pragma unroll
      for (int b = 0; b < FB; ++b) {
        int col = tn + wn + b * 16 + l15;
#pragma unroll
        for (int r = 0; r < 4; ++r)
          Cf[(long long)(mB + r) * g.ldC + col] = acc[a][b][r] / ls[lrow + r];
      }
    }
  } else {
#pragma unroll
    for (int a = 0; a < FA; ++a) {
      int mB = tm + wm + a * 16 + quad * 4;
#pragma unroll
      for (int b = 0; b < FB; ++b) {
        int col = tn + wn + b * 16 + l15;
#pragma unroll
        for (int r = 0; r < 4; ++r) {
          float val = acc[a][b][r];
          if constexpr (MODE == M_RELU) val = val > 0.f ? val : 0.f;
          if constexpr (MODE == M_F32) {
            float* Cf = g.Cf + e * g.sCe + i * g.sCi;
            Cf[(long long)(mB + r) * g.ldC + col] = val;
          } else {
            bf16* C = g.C + e * g.sCe + i * g.sCi;
            C[(long long)(mB + r) * g.ldC + col] = (bf16)val;
          }
        }
      }
    }
  }
}

// ---------------- unified weight prep: all transposes + Wv plain cast, one dispatch ----------------
__global__ __launch_bounds__(256)
void prep_weights(const float* qa, const float* qb, const float* oa, const float* ob,
                  const float* w1a, const float* w1b, const float* w2a, const float* w2b,
                  bf16* wqkvT, bf16* wrT, bf16* wvPlain, bf16* woT, bf16* w1T, bf16* w2T) {
  int id = blockIdx.x;
  const float* src; bf16* dst; int R, C, tx, ty; bool plain = false;
  if (id < 3072) {          // Wqkvr: 48 mats x 64 tiles
    int mat = id >> 6, tile = id & 63;
    tx = tile & 7; ty = tile >> 3;
    int e = mat / 24, rj = mat % 24, j = rj >> 2, c = rj & 3;
    src = (e ? qb : qa) + (long long)(j * 4 + c) * 262144;
    R = 512; C = 512;
    if (c < 2)        dst = wqkvT + ((long long)(e * 6 + j) * 3 + c) * 262144;
    else if (c == 2) { dst = wvPlain + (long long)(e * 6 + j) * 262144; plain = true; }
    else              dst = wrT + (long long)(e * 6 + j) * 262144;
  } else if (id < 3840) {   // Wo: 12 mats x 64 tiles
    int id2 = id - 3072; int mat = id2 >> 6, tile = id2 & 63;
    tx = tile & 7; ty = tile >> 3;
    int e = mat / 6, j = mat % 6;
    src = (e ? ob : oa) + (long long)j * 262144;
    dst = woT + (long long)mat * 262144; R = 512; C = 512;
  } else if (id < 6912) {   // W1 (512x2048): 12 mats x 256 tiles
    int id2 = id - 3840; int mat = id2 >> 8, tile = id2 & 255;
    tx = tile & 31; ty = tile >> 5;
    int e = mat / 6, j = mat % 6;
    src = (e ? w1b : w1a) + (long long)j * 512 * 2048;
    dst = w1T + (long long)mat * 512 * 2048; R = 512; C = 2048;
  } else {                  // W2 (2048x512): 12 mats x 256 tiles
    int id2 = id - 6912; int mat = id2 >> 8, tile = id2 & 255;
    tx = tile & 7; ty = tile >> 3;
    int e = mat / 6, j = mat % 6;
    src = (e ? w2b : w2a) + (long long)j * 2048 * 512;
    dst = w2T + (long long)mat * 2048 * 512; R = 2048; C = 512;
  }
  int c0 = tx * 64, r0 = ty * 64;
  int x = threadIdx.x, y = threadIdx.y;
  if (plain) {
    for (int k = 0; k < 16; ++k) {
      int rr = y + k * 4;
      dst[(long long)(r0 + rr) * C + c0 + x] = (bf16)src[(long long)(r0 + rr) * C + c0 + x];
    }
  } else {
    __shared__ bf16 t[64][65];
    for (int k = 0; k < 16; ++k) {
      int rr = y + k * 4;
      t[rr][x] = (bf16)src[(long long)(r0 + rr) * C + c0 + x];
    }
    __syncthreads();
    for (int k = 0; k < 16; ++k) {
      int rr = y + k * 4;
      dst[(long long)(c0 + rr) * R + r0 + x] = t[x][rr];
    }
  }
}

// ---------------- misc setup kernels ----------------
__global__ __launch_bounds__(256)
void sinusoid_kernel(bf16* rb) {
  int i = blockIdx.x, m = threadIdx.x;
  float p = (float)(1535 - i);
  float inv = expf(-((float)(2 * m) * (1.0f / 512.0f)) * 9.210340371976184f);
  float ang = p * inv;
  rb[(long long)i * 512 + 2 * m]     = (bf16)sinf(ang);
  rb[(long long)i * 512 + 2 * m + 1] = (bf16)cosf(ang);
}

__global__ __launch_bounds__(128)
void embed_kernel(const int* src, const float* emb, bf16* Sb, float* Sf) {
  int row = blockIdx.x, e = blockIdx.y, tid = threadIdx.x;
  int tok = e ? src[4095 - row] : src[row];
  long long base = ((long long)e * TOK + row) * 512 + tid * 4;
  float4 f = *(const float4*)&emb[(long long)tok * 512 + tid * 4];
  *(float4*)&Sf[base] = f;
  Sb[base + 0] = (bf16)f.x; Sb[base + 1] = (bf16)f.y;
  Sb[base + 2] = (bf16)f.z; Sb[base + 3] = (bf16)f.w;
}

// zero the "no-memory" regions: kbuf rows 0..1023, vwoT cols 0..1023
__global__ __launch_bounds__(256)
void zero_kv(bf16* kbuf, bf16* vwoT) {
  int r = blockIdx.x, e = blockIdx.y, which = blockIdx.z, tid = threadIdx.x;
  if (which == 0) {
    bf16* p = kbuf + ((long long)e * KBROWS + r) * 512;
    p[tid] = (bf16)0.f; p[tid + 256] = (bf16)0.f;
  } else if (r < 512) {
    bf16* p = vwoT + ((long long)e * 512 + r) * KBROWS;
#pragma unroll
    for (int k = 0; k < 4; ++k) p[tid + k * 256] = (bf16)0.f;
  }
}

// ---------------- residual + layernorm; outMode 1 = write final output directly ----------------
__global__ __launch_bounds__(64)
void ln_kernel(const float* Xf, const float* Tf, const float* lnA, const float* lnB,
               int gOff, bf16* OutB, float* OutF, int outMode, float* finalOut) {
  int row = blockIdx.x, e = blockIdx.y;
  long long base = ((long long)e * TOK + row) * 512;
  const float* x = Xf + base;
  const float* t = Tf + base;
  const float* ln = e ? lnB : lnA;
  const float* gm = ln + gOff;
  const float* bt = ln + gOff + 512;
  int lane = threadIdx.x;
  float vals[8];
  float s = 0.f;
#pragma unroll
  for (int k = 0; k < 8; ++k) { int d = lane + k * 64; vals[k] = x[d] + t[d]; s += vals[k]; }
  for (int off = 32; off; off >>= 1) s += __shfl_xor(s, off);
  float mu = s * (1.0f / 512.0f);
  float vs = 0.f;
#pragma unroll
  for (int k = 0; k < 8; ++k) { float d0 = vals[k] - mu; vs += d0 * d0; }
  for (int off = 32; off; off >>= 1) vs += __shfl_xor(vs, off);
  float rstd = rsqrtf(vs * (1.0f / 512.0f) + 1e-5f);
  if (outMode == 0) {
#pragma unroll
    for (int k = 0; k < 8; ++k) {
      int d = lane + k * 64;
      float y = (vals[k] - mu) * rstd * gm[d] + bt[d];
      OutB[base + d] = (bf16)y;
      OutF[base + d] = y;
    }
  } else {
    long long ob = e ? ((long long)(4095 - row) * 1024 + 512) : ((long long)row * 1024);
#pragma unroll
    for (int k = 0; k < 8; ++k) {
      int d = lane + k * 64;
      finalOut[ob + d] = (vals[k] - mu) * rstd * gm[d] + bt[d];
    }
  }
}

extern "C" void kernel_launch(void* const* d_in, const int* in_sizes, int n_in,
                              void* d_out, int out_size, void* d_ws, size_t ws_size,
                              hipStream_t stream) {
  const int*   src   = (const int*)d_in[0];
  const float* emb   = (const float*)d_in[2];
  const float* Wq_a  = (const float*)d_in[3];
  const float* Wo_a  = (const float*)d_in[4];
  const float* W1_a  = (const float*)d_in[5];
  const float* W2_a  = (const float*)d_in[6];
  const float* ln_a  = (const float*)d_in[7];
  const float* uv_a  = (const float*)d_in[8];
  const float* Wq_b  = (const float*)d_in[9];
  const float* Wo_b  = (const float*)d_in[10];
  const float* W1_b  = (const float*)d_in[11];
  const float* W2_b  = (const float*)d_in[12];
  const float* ln_b  = (const float*)d_in[13];
  const float* uv_b  = (const float*)d_in[14];
  float* out = (float*)d_out;

  char* w = (char*)d_ws;
  size_t off = 0;
  auto alloc = [&](long long elems, int esz) -> char* {
    char* p = w + off;
    off += (size_t)elems * esz;
    off = (off + 255) & ~(size_t)255;
    return p;
  };
  bf16* wqkvT = (bf16*)alloc(2LL * 6 * 1536 * 512, 2);  // rows: q, k, (wvo = Wv@Wo set at runtime)
  bf16* woT   = (bf16*)alloc(2LL * 6 * 512 * 512, 2);
  bf16* w1T   = (bf16*)alloc(2LL * 6 * 2048 * 512, 2);
  bf16* w2T   = (bf16*)alloc(2LL * 6 * 512 * 2048, 2);
  bf16* pk    = (bf16*)alloc(2LL * 6 * 1536 * 512, 2);
  bf16* Sb    = (bf16*)alloc(2LL * TOK * 512, 2);
  float* Sf   = (float*)alloc(2LL * TOK * 512, 4);
  bf16* quv   = (bf16*)alloc(2LL * TOK * 1024, 2);
  bf16* kbuf  = (bf16*)alloc(2LL * KBROWS * 512, 2);
  bf16* vwoT  = (bf16*)alloc(2LL * 512 * KBROWS, 2);
  bf16* P     = (bf16*)alloc(2LL * 8 * 512 * 1536, 2);
  float* t1f  = (float*)alloc(2LL * TOK * 512, 4);
  bf16* f1    = (bf16*)alloc(2LL * TOK * 2048, 2);
  // overlays (setup-only, inside f1's region; f1 first written in layer loop):
  bf16* rb      = f1;                          // 1.5 MB
  bf16* wrT     = f1 + 1024LL * 1024;          // 6 MB at +2MB
  bf16* wvPlain = f1 + 4096LL * 1024;          // 6 MB at +8MB

  if (off > ws_size) return;

  // ---- setup ----
  prep_weights<<<9984, dim3(64, 4), 0, stream>>>(Wq_a, Wq_b, Wo_a, Wo_b, W1_a, W1_b, W2_a, W2_b,
                                                 wqkvT, wrT, wvPlain, woT, w1T, w2T);
  sinusoid_kernel<<<1536, 256, 0, stream>>>(rb);
  embed_kernel<<<dim3(4096, 2), 128, 0, stream>>>(src, emb, Sb, Sf);
  zero_kv<<<dim3(1024, 2, 2), 256, 0, stream>>>(kbuf, vwoT);

  {  // pk[e][j] = R @ Wr[e][j]
    GemmArgs g = {};
    g.A = rb; g.sAe = 0; g.sAi = 0; g.ldA = 512;
    g.B = wrT; g.sBe = 0; g.sBi = 512LL * 512; g.ldB = 512;
    g.C = pk; g.sCe = 0; g.sCi = 1536LL * 512; g.ldC = 512;
    g.M = 1536; g.N = 512; g.K = 512; g.iPerE = 12;
    gemm_kernel<M_BF16, false, 128, 128><<<dim3(12, 4, 12), 256, 0, stream>>>(g);
  }
  {  // wvoT[e][j][od][k] = Wvo[k][od] = sum_v Wv[k][v] Wo[v][od]  -> wqkvT slot 2
    GemmArgs g = {};
    g.A = woT; g.sAe = 6LL * 262144; g.sAi = 262144; g.ldA = 512;       // A[od][v] = Wo[v][od]
    g.B = wvPlain; g.sBe = 6LL * 262144; g.sBi = 262144; g.ldB = 512;   // B[k][v]  = Wv[k][v]
    g.C = wqkvT + 2LL * 262144; g.sCe = 18LL * 262144; g.sCi = 3LL * 262144; g.ldC = 512;
    g.M = 512; g.N = 512; g.K = 512; g.iPerE = 6;
    gemm_kernel<M_BF16, false, 128, 128><<<dim3(4, 4, 12), 256, 0, stream>>>(g);
  }

  const float scale = 0.044194173824159216f;  // 1/sqrt(512)

  for (int j = 0; j < 6; ++j) {
    {  // QKV: q+u/q+v -> quv, k -> kbuf(+1024), S@Wvo -> vwoT(+1024, transposed)
      GemmArgs g = {};
      g.A = Sb; g.sAe = (long long)TOK * 512; g.sAi = 0; g.ldA = 512;
      g.B = wqkvT + (long long)j * 1536 * 512; g.sBe = 6LL * 1536 * 512; g.sBi = 0; g.ldB = 512;
      g.M = TOK; g.N = 1536; g.K = 512; g.iPerE = 1;
      g.quv = quv; g.kbuf = kbuf; g.vt = vwoT; g.uvA = uv_a; g.uvB = uv_b;
      gemm_kernel<M_QKV, false, 128, 128><<<dim3(32, 12, 2), 256, 0, stream>>>(g);
    }
    {  // P = exp(qu@Kwin^T + qv@pk^T scaled+masked)  (no-max softmax numerator)
      GemmArgs g = {};
      g.A = quv; g.sAe = (long long)TOK * 1024; g.sAi = 512LL * 1024; g.ldA = 1024;
      g.B = kbuf; g.sBe = (long long)KBROWS * 512; g.sBi = 512LL * 512; g.ldB = 512;
      g.B2 = pk + (long long)j * 1536 * 512; g.sB2e = 6LL * 1536 * 512; g.ldB2 = 512;
      g.C = P; g.sCe = 8LL * 512 * 1536; g.sCi = 512LL * 1536; g.ldC = 1536;
      g.M = 512; g.N = 1536; g.K = 1024; g.iPerE = 8;
      g.scale = scale;
      gemm_kernel<M_SCOREXP, true, 128, 128><<<dim3(4, 12, 16), 256, 0, stream>>>(g);
    }
    {  // attn_proj = (P @ VWowin) / rowsum(P)  -> fp32 t1f
      GemmArgs g = {};
      g.A = P; g.sAe = 8LL * 512 * 1536; g.sAi = 512LL * 1536; g.ldA = 1536;
      g.B = vwoT; g.sBe = 512LL * KBROWS; g.sBi = 512; g.ldB = KBROWS;
      g.Cf = t1f; g.sCe = (long long)TOK * 512; g.sCi = 512LL * 512; g.ldC = 512;
      g.M = 512; g.N = 512; g.K = 1536; g.iPerE = 8;
      gemm_kernel<M_PV, false, 64, 128><<<dim3(8, 4, 16), 256, 0, stream>>>(g);
    }
    // H = LN(state + attn_out) — in-place into Sb/Sf
    ln_kernel<<<dim3(4096, 2), 64, 0, stream>>>(Sf, t1f, ln_a, ln_b, (j * 4 + 0) * 512, Sb, Sf, 0, out);
    {  // F1 = relu(H @ W1)
      GemmArgs g = {};
      g.A = Sb; g.sAe = (long long)TOK * 512; g.sAi = 0; g.ldA = 512;
      g.B = w1T + (long long)j * 2048 * 512; g.sBe = 6LL * 2048 * 512; g.sBi = 0; g.ldB = 512;
      g.C = f1; g.sCe = (long long)TOK * 2048; g.sCi = 0; g.ldC = 2048;
      g.M = TOK; g.N = 2048; g.K = 512; g.iPerE = 1;
      gemm_kernel<M_RELU, false, 128, 128><<<dim3(32, 16, 2), 256, 0, stream>>>(g);
    }
    {  // T1 = F1 @ W2 (fp32 out)
      GemmArgs g = {};
      g.A = f1; g.sAe = (long long)TOK * 2048; g.sAi = 0; g.ldA = 2048;
      g.B = w2T + (long long)j * 512 * 2048; g.sBe = 6LL * 512 * 2048; g.sBi = 0; g.ldB = 2048;
      g.Cf = t1f; g.sCe = (long long)TOK * 512; g.sCi = 0; g.ldC = 512;
      g.M = TOK; g.N = 512; g.K = 2048; g.iPerE = 1;
      gemm_kernel<M_F32, false, 64, 128><<<dim3(64, 4, 2), 256, 0, stream>>>(g);
    }
    // state = LN(H + ff); last layer writes final output directly (concat + reverse fused)
    ln_kernel<<<dim3(4096, 2), 64, 0, stream>>>(Sf, t1f, ln_a, ln_b, (j * 4 + 2) * 512, Sb, Sf,
                                                (j == 5) ? 1 : 0, out);
  }
}